// Round 2
// baseline (239.020 us; speedup 1.0000x reference)
//
#include <hip/hip_runtime.h>
#include <hip/hip_bf16.h>

typedef unsigned short u16;
typedef __bf16 bf16x8 __attribute__((ext_vector_type(8)));
typedef float f32x4 __attribute__((ext_vector_type(4)));

#define BQ 4
#define LQ 2048
#define DQ 256
#define NROWQ (BQ * LQ)

__device__ __forceinline__ float bf2f(u16 u) {
  return __uint_as_float(((unsigned int)u) << 16);
}
__device__ __forceinline__ u16 f2bf(float f) {
  unsigned int x = __float_as_uint(f);
  x += 0x7fffu + ((x >> 16) & 1u);
  return (u16)(x >> 16);
}
__device__ __forceinline__ float waveSum(float v) {
#pragma unroll
  for (int o = 32; o > 0; o >>= 1) v += __shfl_down(v, o, 64);
  return v;
}
__device__ __forceinline__ float waveMax(float v) {
#pragma unroll
  for (int o = 32; o > 0; o >>= 1) v = fmaxf(v, __shfl_down(v, o, 64));
  return v;
}

// ---------------------------------------------------------------------------
// Generic bf16 MFMA GEMM:  C[row, col] = sum_k A[row, k] * B[col, k]  (+bias)
// A: [M, K] row-major bf16 bits; B: [N, K] row-major bf16 bits (i.e. B^T form)
// C: fp32 (OUTBF=0) or bf16 bits (OUTBF=1), ldc = N. Batched via blockIdx.z.
// Tile 64x64, BK=32, 256 threads (4 waves, 2x2), 2x2 MFMA 16x16x32 per wave.
// bias (optional) is fp32.
// ---------------------------------------------------------------------------
template <int OUTBF>
__global__ __launch_bounds__(256) void gemm_abT(
    const u16* __restrict__ A, const u16* __restrict__ B, void* __restrict__ Cv,
    const float* __restrict__ bias, int N, int K,
    long long sA, long long sB, long long sC) {
  __shared__ u16 As[64][40];  // +8 pad
  __shared__ u16 Bs[64][40];
  const int bz = blockIdx.z;
  const u16* Ap = A + (long long)bz * sA;
  const u16* Bp = B + (long long)bz * sB;
  const int bm = blockIdx.x * 64, bn = blockIdx.y * 64;
  const int tid = threadIdx.x;
  const int lane = tid & 63, wid = tid >> 6;
  const int wm = (wid >> 1) * 32, wn = (wid & 1) * 32;
  const int ldrow = tid >> 2, ldcol = (tid & 3) * 8;
  const int fm = lane & 15, fq = (lane >> 4) * 8;
  f32x4 acc00 = {}, acc01 = {}, acc10 = {}, acc11 = {};
  const u16* aptr = Ap + (long long)(bm + ldrow) * K + ldcol;
  const u16* bptr = Bp + (long long)(bn + ldrow) * K + ldcol;
  for (int k0 = 0; k0 < K; k0 += 32) {
    uint4 av = *(const uint4*)(aptr + k0);
    uint4 bv = *(const uint4*)(bptr + k0);
    __syncthreads();
    *(uint4*)&As[ldrow][ldcol] = av;
    *(uint4*)&Bs[ldrow][ldcol] = bv;
    __syncthreads();
    bf16x8 a0 = *(const bf16x8*)&As[wm + fm][fq];
    bf16x8 a1 = *(const bf16x8*)&As[wm + 16 + fm][fq];
    bf16x8 b0 = *(const bf16x8*)&Bs[wn + fm][fq];
    bf16x8 b1 = *(const bf16x8*)&Bs[wn + 16 + fm][fq];
    acc00 = __builtin_amdgcn_mfma_f32_16x16x32_bf16(a0, b0, acc00, 0, 0, 0);
    acc01 = __builtin_amdgcn_mfma_f32_16x16x32_bf16(a0, b1, acc01, 0, 0, 0);
    acc10 = __builtin_amdgcn_mfma_f32_16x16x32_bf16(a1, b0, acc10, 0, 0, 0);
    acc11 = __builtin_amdgcn_mfma_f32_16x16x32_bf16(a1, b1, acc11, 0, 0, 0);
  }
  const int colq = lane & 15, rowq = (lane >> 4) * 4;
  f32x4 accs[2][2] = {{acc00, acc01}, {acc10, acc11}};
#pragma unroll
  for (int mt = 0; mt < 2; ++mt) {
#pragma unroll
    for (int nt = 0; nt < 2; ++nt) {
      int col = bn + wn + nt * 16 + colq;
      int row0 = bm + wm + mt * 16 + rowq;
      float bb = bias ? bias[col] : 0.0f;
#pragma unroll
      for (int r = 0; r < 4; ++r) {
        long long idx = sC * bz + (long long)(row0 + r) * N + col;
        float v = accs[mt][nt][r] + bb;
        if (OUTBF) ((u16*)Cv)[idx] = f2bf(v);
        else ((float*)Cv)[idx] = v;
      }
    }
  }
}

// ---------------------------------------------------------------------------
// dtype convert: f32 -> bf16, vectorized x4
// ---------------------------------------------------------------------------
__global__ __launch_bounds__(256) void f2b_copy(const float* __restrict__ src,
                                                u16* __restrict__ dst) {
  int i = blockIdx.x * 256 + threadIdx.x;
  float4 v = ((const float4*)src)[i];
  ushort4 o;
  o.x = f2bf(v.x); o.y = f2bf(v.y); o.z = f2bf(v.z); o.w = f2bf(v.w);
  ((ushort4*)dst)[i] = o;
}

// ---------------------------------------------------------------------------
// Transposes
// ---------------------------------------------------------------------------
__global__ __launch_bounds__(256) void transpose_b16(
    const u16* __restrict__ src, u16* __restrict__ dst, int R, int C,
    long long sS, long long sD) {
  __shared__ u16 t[32][33];
  const u16* s = src + (long long)blockIdx.z * sS;
  u16* d = dst + (long long)blockIdx.z * sD;
  int r0 = blockIdx.y * 32, c0 = blockIdx.x * 32;
  int x = threadIdx.x, y = threadIdx.y;
#pragma unroll
  for (int i = 0; i < 32; i += 8) t[y + i][x] = s[(long long)(r0 + y + i) * C + c0 + x];
  __syncthreads();
#pragma unroll
  for (int i = 0; i < 32; i += 8) d[(long long)(c0 + y + i) * R + r0 + x] = t[x][y + i];
}

__global__ __launch_bounds__(256) void transpose_f2b(
    const float* __restrict__ src, u16* __restrict__ dst, int R, int C,
    long long sS, long long sD) {
  __shared__ u16 t[32][33];
  const float* s = src + (long long)blockIdx.z * sS;
  u16* d = dst + (long long)blockIdx.z * sD;
  int r0 = blockIdx.y * 32, c0 = blockIdx.x * 32;
  int x = threadIdx.x, y = threadIdx.y;
#pragma unroll
  for (int i = 0; i < 32; i += 8) t[y + i][x] = f2bf(s[(long long)(r0 + y + i) * C + c0 + x]);
  __syncthreads();
#pragma unroll
  for (int i = 0; i < 32; i += 8) d[(long long)(c0 + y + i) * R + r0 + x] = t[x][y + i];
}

// weights are f32 [256,256]; write bf16 transposed
__global__ __launch_bounds__(256) void transpose_w4(
    const float* s0, const float* s1, const float* s2, const float* s3,
    u16* d0, u16* d1, u16* d2, u16* d3) {
  int z = blockIdx.z;
  const float* s = z == 0 ? s0 : z == 1 ? s1 : z == 2 ? s2 : s3;
  u16* d = z == 0 ? d0 : z == 1 ? d1 : z == 2 ? d2 : d3;
  __shared__ u16 t[32][33];
  int r0 = blockIdx.y * 32, c0 = blockIdx.x * 32;
  int x = threadIdx.x, y = threadIdx.y;
#pragma unroll
  for (int i = 0; i < 32; i += 8) t[y + i][x] = f2bf(s[(r0 + y + i) * 256 + c0 + x]);
  __syncthreads();
#pragma unroll
  for (int i = 0; i < 32; i += 8) d[(c0 + y + i) * 256 + r0 + x] = t[x][y + i];
}

// ---------------------------------------------------------------------------
// Elementwise / reduction kernels
// ---------------------------------------------------------------------------
// rotary + d^-0.25 scale + diag (0.5*sum(x^2)); one block per (b,l) row
__global__ __launch_bounds__(256) void rot_scale_diag(
    const float* __restrict__ lin, const float* __restrict__ pos,
    u16* __restrict__ outb, float* __restrict__ diag) {
  int i = blockIdx.x;
  int l = i & (LQ - 1);
  int d = threadIdx.x;
  float x = lin[(long long)i * DQ + d];
  float xo = lin[(long long)i * DQ + (d ^ 1)];
  float x2 = (d & 1) ? xo : -xo;
  float c = pos[l * DQ + (d | 1)];
  float s = pos[l * DQ + (d & ~1)];
  float r = 0.25f * (x * c + x2 * s);
  outb[(long long)i * DQ + d] = f2bf(r);
  float p = waveSum(r * r);
  __shared__ float red[4];
  int lane = d & 63, wid = d >> 6;
  if (lane == 0) red[wid] = p;
  __syncthreads();
  if (d == 0) diag[i] = 0.5f * (red[0] + red[1] + red[2] + red[3]);
}

__global__ __launch_bounds__(256) void maxk_part(const float* __restrict__ xp,
                                                 float* __restrict__ part) {
  int b = blockIdx.y, ch = blockIdx.x, tid = threadIdx.x;
  const float* p = xp + (long long)b * LQ * DQ + (long long)ch * 8192;
  float m = -3.0e38f;
  for (int j = tid; j < 8192; j += 256) m = fmaxf(m, p[j]);
  m = waveMax(m);
  __shared__ float red[4];
  if ((tid & 63) == 0) red[tid >> 6] = m;
  __syncthreads();
  if (tid == 0) part[b * 64 + ch] = fmaxf(fmaxf(red[0], red[1]), fmaxf(red[2], red[3]));
}

__global__ void maxk_final(const float* __restrict__ part, float* __restrict__ mxk) {
  int tid = threadIdx.x;  // 256 threads: wave w reduces batch w
  int b = tid >> 6, lane = tid & 63;
  float m = waveMax(part[b * 64 + lane]);
  if (lane == 0) mxk[b] = m;
}

__global__ __launch_bounds__(256) void kp_kern(
    const float* __restrict__ xp, const float* __restrict__ diag,
    const float* __restrict__ mxk, u16* __restrict__ kp) {
  int i = blockIdx.x, t = threadIdx.x, b = i >> 11;
  float v = 0.0625f * (__expf(xp[(long long)i * DQ + t] - diag[i] - mxk[b]) + 1e-6f);
  kp[(long long)i * DQ + t] = f2bf(v);
}

__global__ void ksum_init(float* __restrict__ ksum) {
  ksum[blockIdx.x * 256 + threadIdx.x] = 0.0f;
}

__global__ __launch_bounds__(256) void ksum_kern(const u16* __restrict__ kp,
                                                 float* __restrict__ ksum) {
  int b = blockIdx.y, ch = blockIdx.x, t = threadIdx.x;  // grid (32, 4)
  const u16* p = kp + (long long)b * LQ * DQ + (long long)ch * 64 * DQ;
  float acc = 0.0f;
#pragma unroll 4
  for (int l = 0; l < 64; ++l) acc += bf2f(p[l * DQ + t]);
  atomicAdd(&ksum[b * DQ + t], acc);
}

// row max + exp + qp(bf16) + den = sum_m qp_bf16 * ksum  (consistent rounding)
__global__ __launch_bounds__(256) void qp_kern(
    const float* __restrict__ xp, const float* __restrict__ diag,
    const float* __restrict__ ksum, u16* __restrict__ qp,
    float* __restrict__ den) {
  int i = blockIdx.x, t = threadIdx.x, b = i >> 11;
  float x = xp[(long long)i * DQ + t];
  __shared__ float red[4];
  __shared__ float mxs;
  int lane = t & 63, wid = t >> 6;
  float m = waveMax(x);
  if (lane == 0) red[wid] = m;
  __syncthreads();
  if (t == 0) mxs = fmaxf(fmaxf(red[0], red[1]), fmaxf(red[2], red[3]));
  __syncthreads();
  float v = 0.0625f * (__expf(x - diag[i] - mxs) + 1e-6f);
  u16 vb = f2bf(v);
  qp[(long long)i * DQ + t] = vb;
  float dv = bf2f(vb) * ksum[b * DQ + t];
  float sv = waveSum(dv);
  __syncthreads();
  if (lane == 0) red[wid] = sv;
  __syncthreads();
  if (t == 0) den[i] = red[0] + red[1] + red[2] + red[3];
}

__global__ __launch_bounds__(256) void ctx_kern(const float* __restrict__ num,
                                                const float* __restrict__ den,
                                                u16* __restrict__ ctx) {
  int i = blockIdx.x, t = threadIdx.x;
  ctx[(long long)i * DQ + t] = f2bf(num[(long long)i * DQ + t] / den[i]);
}

// ---------------------------------------------------------------------------
extern "C" void kernel_launch(void* const* d_in, const int* in_sizes, int n_in,
                              void* d_out, int out_size, void* d_ws, size_t ws_size,
                              hipStream_t stream) {
  (void)in_sizes; (void)n_in; (void)out_size; (void)ws_size;
  const float* query = (const float*)d_in[0];
  const float* key = (const float*)d_in[1];
  const float* value = (const float*)d_in[2];
  // d_in[3] = mask: unused by the reference
  const float* Wq = (const float*)d_in[4];
  const float* bq = (const float*)d_in[5];
  const float* Wk = (const float*)d_in[6];
  const float* bk = (const float*)d_in[7];
  const float* Wv = (const float*)d_in[8];
  const float* bv = (const float*)d_in[9];
  const float* Wo = (const float*)d_in[10];
  const float* bo = (const float*)d_in[11];
  const float* proj = (const float*)d_in[12];
  const float* pos = (const float*)d_in[13];

  char* w = (char*)d_ws;  // ~51 MB used
  float* q_lin = (float*)(w);                  // 8 MB ; reused as num
  float* k_lin = (float*)(w + (8 << 20));      // 8 MB ; reused as xp
  u16* xb = (u16*)(w + (16 << 20));            // 4 MB (bf16 staging for q/k/v)
  u16* v_bf = (u16*)(w + (20 << 20));          // 4 MB
  u16* vT = (u16*)(w + (24 << 20));            // 4 MB
  u16* qs = (u16*)(w + (28 << 20));            // 4 MB
  u16* ks = (u16*)(w + (32 << 20));            // 4 MB
  u16* kp = (u16*)(w + (36 << 20));            // 4 MB
  u16* kpT = (u16*)(w + (40 << 20));           // 4 MB ; reused as ctx
  u16* qp = (u16*)(w + (44 << 20));            // 4 MB
  u16* WqT = (u16*)(w + (48 << 20));           // 128 KB each
  u16* WkT = WqT + 65536;
  u16* WvT = WkT + 65536;
  u16* WoT = WvT + 65536;
  u16* projb = WoT + 65536;                    // 128 KB
  float* kvs = (float*)(w + (48 << 20) + (640 << 10));   // 1 MB
  u16* kvsT = (u16*)(w + (48 << 20) + (1664 << 10));     // 512 KB
  float* diag_q = (float*)(w + (50 << 20) + (256 << 10));  // 32 KB
  float* diag_k = diag_q + NROWQ;              // 32 KB
  float* part = diag_k + NROWQ;                // 1 KB
  float* mxk = part + 256;
  float* ksum = mxk + 64;                      // 4 KB
  float* den = ksum + 1024;                    // 32 KB
  float* num = q_lin;
  float* xp = k_lin;
  u16* ctx = kpT;

  dim3 blk256(256);
  dim3 blkT(32, 8);

  // 0. weights f32 -> bf16 transposed; proj f32 -> bf16
  transpose_w4<<<dim3(8, 8, 4), blkT, 0, stream>>>(Wq, Wk, Wv, Wo, WqT, WkT, WvT, WoT);
  f2b_copy<<<dim3(64), blk256, 0, stream>>>(proj, projb);
  // 1-6. input projections (convert each input to bf16, then GEMM; xb reused)
  f2b_copy<<<dim3(2048), blk256, 0, stream>>>(query, xb);
  gemm_abT<0><<<dim3(128, 4, 1), blk256, 0, stream>>>(xb, WqT, q_lin, bq, 256, 256, 0, 0, 0);
  f2b_copy<<<dim3(2048), blk256, 0, stream>>>(key, xb);
  gemm_abT<0><<<dim3(128, 4, 1), blk256, 0, stream>>>(xb, WkT, k_lin, bk, 256, 256, 0, 0, 0);
  f2b_copy<<<dim3(2048), blk256, 0, stream>>>(value, xb);
  gemm_abT<1><<<dim3(128, 4, 1), blk256, 0, stream>>>(xb, WvT, v_bf, bv, 256, 256, 0, 0, 0);
  // 7-8. rotary + scale + diag
  rot_scale_diag<<<dim3(NROWQ), blk256, 0, stream>>>(q_lin, pos, qs, diag_q);
  rot_scale_diag<<<dim3(NROWQ), blk256, 0, stream>>>(k_lin, pos, ks, diag_k);
  // 9. xp_k = ks @ proj^T (xp aliases k_lin, consumed in step 8)
  gemm_abT<0><<<dim3(128, 4, 1), blk256, 0, stream>>>(ks, projb, xp, nullptr, 256, 256, 0, 0, 0);
  // 10-11. per-batch global max of xp_k
  maxk_part<<<dim3(64, 4), blk256, 0, stream>>>(xp, part);
  maxk_final<<<dim3(1), blk256, 0, stream>>>(part, mxk);
  // 12. kp
  kp_kern<<<dim3(NROWQ), blk256, 0, stream>>>(xp, diag_k, mxk, kp);
  // 13-14. ksum[b,m] = sum_l kp
  ksum_init<<<dim3(4), blk256, 0, stream>>>(ksum);
  ksum_kern<<<dim3(32, 4), blk256, 0, stream>>>(kp, ksum);
  // 15-16. transposes for kvs GEMM
  transpose_b16<<<dim3(8, 64, 4), blkT, 0, stream>>>(kp, kpT, 2048, 256, 524288, 524288);
  transpose_b16<<<dim3(8, 64, 4), blkT, 0, stream>>>(v_bf, vT, 2048, 256, 524288, 524288);
  // 17. kvs[b] = kp[b]^T @ v[b]   (M=256, N=256, K=2048, batch=4)
  gemm_abT<0><<<dim3(4, 4, 4), blk256, 0, stream>>>(kpT, vT, kvs, nullptr, 256, 2048, 524288, 524288, 65536);
  // 18. kvsT (fp32 -> bf16 transpose)
  transpose_f2b<<<dim3(8, 8, 4), blkT, 0, stream>>>(kvs, kvsT, 256, 256, 65536, 65536);
  // 19. xp_q = qs @ proj^T (reuses xp buffer)
  gemm_abT<0><<<dim3(128, 4, 1), blk256, 0, stream>>>(qs, projb, xp, nullptr, 256, 256, 0, 0, 0);
  // 20. qp + den
  qp_kern<<<dim3(NROWQ), blk256, 0, stream>>>(xp, diag_q, ksum, qp, den);
  // 21. num[b] = qp[b] @ kvs[b]   (M=2048, N=256, K=256, batch=4) ; kpT free -> ctx
  gemm_abT<0><<<dim3(32, 4, 4), blk256, 0, stream>>>(qp, kvsT, num, nullptr, 256, 256, 524288, 65536, 524288);
  // 22. ctx = num / den
  ctx_kern<<<dim3(NROWQ), blk256, 0, stream>>>(num, den, ctx);
  // 23. out = ctx @ Wo + bo  -> fp32 d_out
  gemm_abT<0><<<dim3(128, 4, 1), blk256, 0, stream>>>(ctx, WoT, (float*)d_out, bo, 256, 256, 0, 0, 0);
}

// Round 4
// 193.357 us; speedup vs baseline: 1.2362x; 1.2362x over previous
//
#include <hip/hip_runtime.h>

typedef unsigned short u16;
typedef unsigned int u32;
typedef __bf16 bf16x8 __attribute__((ext_vector_type(8)));
typedef float f32x4 __attribute__((ext_vector_type(4)));

__device__ __forceinline__ float bf2f(u16 u) { return __uint_as_float(((u32)u) << 16); }
__device__ __forceinline__ u16 f2bf(float f) {
  u32 x = __float_as_uint(f);
  x += 0x7fffu + ((x >> 16) & 1u);
  return (u16)(x >> 16);
}
// monotone float<->uint encoding for atomicMax on floats
__device__ __forceinline__ u32 encf(float x) {
  u32 u = __float_as_uint(x);
  return (u >> 31) ? ~u : (u | 0x80000000u);
}
__device__ __forceinline__ float decf(u32 e) {
  return (e >> 31) ? __uint_as_float(e & 0x7fffffffu) : __uint_as_float(~e);
}

#define MFMA(a, b, c) __builtin_amdgcn_mfma_f32_16x16x32_bf16(a, b, c, 0, 0, 0)

// ---------------------------------------------------------------------------
// prep_w: z<4: W f32 [256][256] -> bf16 transposed; z==4: proj f32 -> bf16 copy
// ---------------------------------------------------------------------------
__global__ __launch_bounds__(256) void prep_w(
    const float* Wq, const float* Wk, const float* Wv, const float* Wo, const float* proj,
    u16* WqT, u16* WkT, u16* WvT, u16* WoT, u16* projb) {
  int z = blockIdx.z;
  const float* s = z == 0 ? Wq : z == 1 ? Wk : z == 2 ? Wv : z == 3 ? Wo : proj;
  u16* d = z == 0 ? WqT : z == 1 ? WkT : z == 2 ? WvT : z == 3 ? WoT : projb;
  __shared__ u16 t[32][33];
  int r0 = blockIdx.y * 32, c0 = blockIdx.x * 32;
  int x = threadIdx.x, y = threadIdx.y;
  if (z < 4) {
#pragma unroll
    for (int i = 0; i < 32; i += 8) t[y + i][x] = f2bf(s[(r0 + y + i) * 256 + c0 + x]);
    __syncthreads();
#pragma unroll
    for (int i = 0; i < 32; i += 8) d[(c0 + y + i) * 256 + r0 + x] = t[x][y + i];
  } else {
#pragma unroll
    for (int i = 0; i < 32; i += 8) d[(r0 + y + i) * 256 + c0 + x] = f2bf(s[(r0 + y + i) * 256 + c0 + x]);
  }
}

__global__ void init_small(float* __restrict__ ksum, u32* __restrict__ mxk) {
  int t = threadIdx.x;
  for (int i = t; i < 1024; i += 256) ksum[i] = 0.0f;
  if (t < 4) mxk[t] = 0u;
}

// ---------------------------------------------------------------------------
// proj_rot: fused (x@W + b) GEMM [64x256 tile, f32 A staged to bf16] + diag
// (pre-rotary, rotation-invariant norm) + rotary via bf16 LDS round-trip.
// grid (128, 1, 2): z=0 query, z=1 key. 256 threads = 4 waves (2x2).
// ---------------------------------------------------------------------------
__global__ __launch_bounds__(256) void proj_rot(
    const float* __restrict__ Xq, const float* __restrict__ Xk,
    const u16* __restrict__ WqT, const u16* __restrict__ WkT,
    const float* __restrict__ bq, const float* __restrict__ bk,
    const float* __restrict__ pos,
    u16* __restrict__ qs, u16* __restrict__ ks,
    float* __restrict__ diag_q, float* __restrict__ diag_k) {
  const int isK = blockIdx.z;
  const float* X = isK ? Xk : Xq;
  const u16* W = isK ? WkT : WqT;
  const float* bias = isK ? bk : bq;
  u16* outp = isK ? ks : qs;
  float* diag = isK ? diag_k : diag_q;
  __shared__ union USM {
    struct { u16 As[64][40]; u16 Bs[256][40]; } s;
    u16 cbuf[64][264];
  } sm;
  __shared__ float dred[2][2][32];
  const int row0 = blockIdx.x * 64;
  const int t = threadIdx.x;
  const int lane = t & 63, wid = t >> 6;
  const int wrow = wid >> 1, wcol = wid & 1;
  const int fm = lane & 15, fq = (lane >> 4) * 8, rowq = (lane >> 4) * 4;
  const int arow = t >> 2, acol = (t & 3) * 8;
  f32x4 acc[2][8] = {};
  for (int k0 = 0; k0 < 256; k0 += 32) {
    float4 a0 = *(const float4*)(X + (long long)(row0 + arow) * 256 + k0 + acol);
    float4 a1 = *(const float4*)(X + (long long)(row0 + arow) * 256 + k0 + acol + 4);
    uint4 bv[4];
#pragma unroll
    for (int p = 0; p < 4; ++p)
      bv[p] = *(const uint4*)(W + (p * 64 + arow) * 256 + k0 + acol);
    __syncthreads();
    u16* ap = &sm.s.As[arow][acol];
    ap[0] = f2bf(a0.x); ap[1] = f2bf(a0.y); ap[2] = f2bf(a0.z); ap[3] = f2bf(a0.w);
    ap[4] = f2bf(a1.x); ap[5] = f2bf(a1.y); ap[6] = f2bf(a1.z); ap[7] = f2bf(a1.w);
#pragma unroll
    for (int p = 0; p < 4; ++p)
      *(uint4*)&sm.s.Bs[p * 64 + arow][acol] = bv[p];
    __syncthreads();
    bf16x8 af0 = *(const bf16x8*)&sm.s.As[wrow * 32 + fm][fq];
    bf16x8 af1 = *(const bf16x8*)&sm.s.As[wrow * 32 + 16 + fm][fq];
#pragma unroll
    for (int j = 0; j < 8; ++j) {
      bf16x8 bf = *(const bf16x8*)&sm.s.Bs[wcol * 128 + j * 16 + fm][fq];
      acc[0][j] = MFMA(af0, bf, acc[0][j]);
      acc[1][j] = MFMA(af1, bf, acc[1][j]);
    }
    __syncthreads();
  }
  // epilogue: bias, diag partials (pre-rotary f32), bf16 cbuf write
  float dsum[2][4] = {};
#pragma unroll
  for (int i = 0; i < 2; ++i) {
#pragma unroll
    for (int j = 0; j < 8; ++j) {
      int col = wcol * 128 + j * 16 + fm;
      float bb = bias[col];
#pragma unroll
      for (int r = 0; r < 4; ++r) {
        float v = acc[i][j][r] + bb;
        dsum[i][r] += v * v;
        sm.cbuf[wrow * 32 + i * 16 + rowq + r][col] = f2bf(v);
      }
    }
  }
#pragma unroll
  for (int o = 1; o < 16; o <<= 1)
#pragma unroll
    for (int i = 0; i < 2; ++i)
#pragma unroll
      for (int r = 0; r < 4; ++r) dsum[i][r] += __shfl_xor(dsum[i][r], o, 64);
  if (fm == 0) {
#pragma unroll
    for (int i = 0; i < 2; ++i)
#pragma unroll
      for (int r = 0; r < 4; ++r) dred[wrow][wcol][i * 16 + rowq + r] = dsum[i][r];
  }
  __syncthreads();
  if (wcol == 0 && fm == 0) {
#pragma unroll
    for (int i = 0; i < 2; ++i)
#pragma unroll
      for (int r = 0; r < 4; ++r) {
        int rr = i * 16 + rowq + r;
        diag[row0 + wrow * 32 + rr] = 0.03125f * (dred[wrow][0][rr] + dred[wrow][1][rr]);
      }
  }
  // rotary phase: read cbuf bf16, apply rot, write bf16 out (coalesced)
  const int rrow = t >> 5, col0 = (t & 31) * 8;
#pragma unroll
  for (int s = 0; s < 8; ++s) {
    int row = s * 8 + rrow;
    int l = (row0 + row) & 2047;
    uint4 cv = *(const uint4*)&sm.cbuf[row][col0];
    const u16* cp = (const u16*)&cv;
    float x[8];
#pragma unroll
    for (int j = 0; j < 8; ++j) x[j] = bf2f(cp[j]);
    float4 p0 = *(const float4*)(pos + (long long)l * 256 + col0);
    float4 p1 = *(const float4*)(pos + (long long)l * 256 + col0 + 4);
    float pp[8] = {p0.x, p0.y, p0.z, p0.w, p1.x, p1.y, p1.z, p1.w};
    u16 ov[8];
#pragma unroll
    for (int j = 0; j < 8; ++j) {
      float x2 = (j & 1) ? x[j - 1] : -x[j + 1];
      float c = pp[j | 1], sn = pp[j & ~1];
      ov[j] = f2bf(0.25f * (x[j] * c + x2 * sn));
    }
    *(uint4*)&outp[(long long)(row0 + row) * 256 + col0] = *(const uint4*)ov;
  }
}

// ---------------------------------------------------------------------------
// feat_k: xp = ks @ projb^T (32x256 tile) -> xp f32 + per-batch atomic max
// ---------------------------------------------------------------------------
__global__ __launch_bounds__(256) void feat_k(
    const u16* __restrict__ ks, const u16* __restrict__ projb,
    float* __restrict__ xp, u32* __restrict__ mxk) {
  __shared__ u16 As[32][40];
  __shared__ u16 Bs[256][40];
  __shared__ float wred[4];
  const int row0 = blockIdx.x * 32;
  const int b = row0 >> 11;
  const int t = threadIdx.x;
  const int lane = t & 63, wid = t >> 6;
  const int wrow = wid >> 1, wcol = wid & 1;
  const int fm = lane & 15, fq = (lane >> 4) * 8, rowq = (lane >> 4) * 4;
  const int arow = t >> 2, acol = (t & 3) * 8;
  f32x4 acc[8] = {};
  for (int k0 = 0; k0 < 256; k0 += 32) {
    uint4 av = {};
    if (t < 128) av = *(const uint4*)(ks + (long long)(row0 + arow) * 256 + k0 + acol);
    uint4 bv[4];
#pragma unroll
    for (int p = 0; p < 4; ++p)
      bv[p] = *(const uint4*)(projb + (p * 64 + arow) * 256 + k0 + acol);
    __syncthreads();
    if (t < 128) *(uint4*)&As[arow][acol] = av;
#pragma unroll
    for (int p = 0; p < 4; ++p) *(uint4*)&Bs[p * 64 + arow][acol] = bv[p];
    __syncthreads();
    bf16x8 af = *(const bf16x8*)&As[wrow * 16 + fm][fq];
#pragma unroll
    for (int j = 0; j < 8; ++j) {
      bf16x8 bf = *(const bf16x8*)&Bs[wcol * 128 + j * 16 + fm][fq];
      acc[j] = MFMA(af, bf, acc[j]);
    }
    __syncthreads();
  }
  float mx = -3.0e38f;
#pragma unroll
  for (int j = 0; j < 8; ++j) {
#pragma unroll
    for (int r = 0; r < 4; ++r) {
      float v = acc[j][r];
      xp[(long long)(row0 + wrow * 16 + rowq + r) * 256 + wcol * 128 + j * 16 + fm] = v;
      mx = fmaxf(mx, v);
    }
  }
#pragma unroll
  for (int o = 32; o > 0; o >>= 1) mx = fmaxf(mx, __shfl_xor(mx, o, 64));
  if (lane == 0) wred[wid] = mx;
  __syncthreads();
  if (t == 0) {
    float m = fmaxf(fmaxf(wred[0], wred[1]), fmaxf(wred[2], wred[3]));
    atomicMax(mxk + b, encf(m));
  }
}

// ---------------------------------------------------------------------------
// feat_q: xp = qs @ projb^T (32x256 tile) + row max + exp + qp bf16 + den
// ---------------------------------------------------------------------------
__global__ __launch_bounds__(256) void feat_q(
    const u16* __restrict__ qs, const u16* __restrict__ projb,
    const float* __restrict__ diag_q, const float* __restrict__ ksum,
    u16* __restrict__ qp, float* __restrict__ den) {
  __shared__ union USM {
    struct { u16 As[32][40]; u16 Bs[256][40]; } s;
    u16 qbuf[32][264];
  } sm;
  __shared__ float rbuf[2][2][16];
  __shared__ float dbuf[2][2][16];
  __shared__ float ksm[256];
  const int row0 = blockIdx.x * 32;
  const int b = row0 >> 11;
  const int t = threadIdx.x;
  const int lane = t & 63, wid = t >> 6;
  const int wrow = wid >> 1, wcol = wid & 1;
  const int fm = lane & 15, fq = (lane >> 4) * 8, rowq = (lane >> 4) * 4;
  const int arow = t >> 2, acol = (t & 3) * 8;
  ksm[t] = ksum[b * 256 + t];
  f32x4 acc[8] = {};
  for (int k0 = 0; k0 < 256; k0 += 32) {
    uint4 av = {};
    if (t < 128) av = *(const uint4*)(qs + (long long)(row0 + arow) * 256 + k0 + acol);
    uint4 bv[4];
#pragma unroll
    for (int p = 0; p < 4; ++p)
      bv[p] = *(const uint4*)(projb + (p * 64 + arow) * 256 + k0 + acol);
    __syncthreads();
    if (t < 128) *(uint4*)&sm.s.As[arow][acol] = av;
#pragma unroll
    for (int p = 0; p < 4; ++p) *(uint4*)&sm.s.Bs[p * 64 + arow][acol] = bv[p];
    __syncthreads();
    bf16x8 af = *(const bf16x8*)&sm.s.As[wrow * 16 + fm][fq];
#pragma unroll
    for (int j = 0; j < 8; ++j) {
      bf16x8 bf = *(const bf16x8*)&sm.s.Bs[wcol * 128 + j * 16 + fm][fq];
      acc[j] = MFMA(af, bf, acc[j]);
    }
    __syncthreads();
  }
  const int l0 = row0 + wrow * 16;
  float rmax[4] = {-3.0e38f, -3.0e38f, -3.0e38f, -3.0e38f};
#pragma unroll
  for (int j = 0; j < 8; ++j)
#pragma unroll
    for (int r = 0; r < 4; ++r) rmax[r] = fmaxf(rmax[r], acc[j][r]);
#pragma unroll
  for (int o = 1; o < 16; o <<= 1)
#pragma unroll
    for (int r = 0; r < 4; ++r) rmax[r] = fmaxf(rmax[r], __shfl_xor(rmax[r], o, 64));
  if (fm == 0) {
#pragma unroll
    for (int r = 0; r < 4; ++r) rbuf[wrow][wcol][rowq + r] = rmax[r];
  }
  __syncthreads();
  float mx[4], dg[4];
#pragma unroll
  for (int r = 0; r < 4; ++r) {
    mx[r] = fmaxf(rmax[r], rbuf[wrow][wcol ^ 1][rowq + r]);
    dg[r] = diag_q[l0 + rowq + r];
  }
  float denp[4] = {};
#pragma unroll
  for (int j = 0; j < 8; ++j) {
    int col = wcol * 128 + j * 16 + fm;
    float ksv = ksm[col];
#pragma unroll
    for (int r = 0; r < 4; ++r) {
      float v = 0.0625f * (__expf(acc[j][r] - dg[r] - mx[r]) + 1e-6f);
      u16 vb = f2bf(v);
      sm.qbuf[wrow * 16 + rowq + r][col] = vb;
      denp[r] += bf2f(vb) * ksv;
    }
  }
#pragma unroll
  for (int o = 1; o < 16; o <<= 1)
#pragma unroll
    for (int r = 0; r < 4; ++r) denp[r] += __shfl_xor(denp[r], o, 64);
  if (fm == 0) {
#pragma unroll
    for (int r = 0; r < 4; ++r) dbuf[wrow][wcol][rowq + r] = denp[r];
  }
  __syncthreads();
  const int rrow = t >> 5, col0 = (t & 31) * 8;
#pragma unroll
  for (int s = 0; s < 4; ++s) {
    int row = s * 8 + rrow;
    *(uint4*)&qp[(long long)(row0 + row) * 256 + col0] = *(const uint4*)&sm.qbuf[row][col0];
  }
  if (wcol == 0 && fm == 0) {
#pragma unroll
    for (int r = 0; r < 4; ++r)
      den[l0 + rowq + r] = dbuf[wrow][0][rowq + r] + dbuf[wrow][1][rowq + r];
  }
}

// ---------------------------------------------------------------------------
// kvs_split: part[z] = kp_chunk^T @ v_chunk, exp fused in transpose-staging,
// ksum accumulated inline (ny==0 blocks). grid (4 mx, 4 ny, 16 = b*4+kc).
// ---------------------------------------------------------------------------
__global__ __launch_bounds__(256) void kvs_split(
    const float* __restrict__ xp, const u16* __restrict__ v_bf,
    const float* __restrict__ diag_k, const u32* __restrict__ mxk,
    float* __restrict__ part, float* __restrict__ ksum) {
  __shared__ union USM {
    struct { u16 As[64][40]; u16 Bs[64][40]; } s;
    float ksbuf[32][65];
  } sm;
  const int mxt = blockIdx.x, ny = blockIdx.y, z = blockIdx.z;
  const int b = z >> 2, kc = z & 3;
  const long long l0 = (long long)b * 2048 + kc * 512;
  const int t = threadIdx.x;
  const int lane = t & 63, wid = t >> 6;
  const int wrow = wid >> 1, wcol = wid & 1;
  const int fm = lane & 15, fq = (lane >> 4) * 8, rowq = (lane >> 4) * 4;
  const float mxv = decf(mxk[b]);
  const int sr = t >> 3, sc = (t & 7) * 8;
  f32x4 acc[2][2] = {};
  float ksp[8] = {};
  for (int s = 0; s < 16; ++s) {
    long long lrow = l0 + s * 32 + sr;
    float4 x0 = *(const float4*)(xp + lrow * 256 + mxt * 64 + sc);
    float4 x1 = *(const float4*)(xp + lrow * 256 + mxt * 64 + sc + 4);
    uint4 vv = *(const uint4*)(v_bf + lrow * 256 + ny * 64 + sc);
    float dgl = diag_k[lrow];
    float xv[8] = {x0.x, x0.y, x0.z, x0.w, x1.x, x1.y, x1.z, x1.w};
    u16 kpv[8];
#pragma unroll
    for (int j = 0; j < 8; ++j) {
      float v = 0.0625f * (__expf(xv[j] - dgl - mxv) + 1e-6f);
      kpv[j] = f2bf(v);
      ksp[j] += bf2f(kpv[j]);
    }
    __syncthreads();
    const u16* vp = (const u16*)&vv;
#pragma unroll
    for (int j = 0; j < 8; ++j) {
      sm.s.As[sc + j][sr] = kpv[j];
      sm.s.Bs[sc + j][sr] = vp[j];
    }
    __syncthreads();
    bf16x8 a0 = *(const bf16x8*)&sm.s.As[wrow * 32 + fm][fq];
    bf16x8 a1 = *(const bf16x8*)&sm.s.As[wrow * 32 + 16 + fm][fq];
    bf16x8 b0 = *(const bf16x8*)&sm.s.Bs[wcol * 32 + fm][fq];
    bf16x8 b1 = *(const bf16x8*)&sm.s.Bs[wcol * 32 + 16 + fm][fq];
    acc[0][0] = MFMA(a0, b0, acc[0][0]);
    acc[0][1] = MFMA(a0, b1, acc[0][1]);
    acc[1][0] = MFMA(a1, b0, acc[1][0]);
    acc[1][1] = MFMA(a1, b1, acc[1][1]);
  }
#pragma unroll
  for (int mt = 0; mt < 2; ++mt)
#pragma unroll
    for (int nt = 0; nt < 2; ++nt)
#pragma unroll
      for (int r = 0; r < 4; ++r)
        part[(long long)z * 65536 +
             (long long)(mxt * 64 + wrow * 32 + mt * 16 + rowq + r) * 256 +
             ny * 64 + wcol * 32 + nt * 16 + fm] = acc[mt][nt][r];
  __syncthreads();  // all frag reads done; safe to alias ksbuf
#pragma unroll
  for (int j = 0; j < 8; ++j) sm.ksbuf[sr][sc + j] = ksp[j];
  __syncthreads();
  if (ny == 0 && t < 64) {
    float ssum = 0.0f;
    for (int r = 0; r < 32; ++r) ssum += sm.ksbuf[r][t];
    atomicAdd(ksum + b * 256 + mxt * 64 + t, ssum);
  }
}

// ---------------------------------------------------------------------------
// reduce_kvsT: kvsT[b][d][m] = bf16( sum_kc part[b*4+kc][m][d] )
// ---------------------------------------------------------------------------
__global__ __launch_bounds__(256) void reduce_kvsT(const float* __restrict__ part,
                                                   u16* __restrict__ kvsT) {
  __shared__ float tb[32][36];
  const int d0 = blockIdx.x * 32, m0 = blockIdx.y * 32, b = blockIdx.z;
  const int t = threadIdx.x;
  const int m = t >> 3, d4 = (t & 7) * 4;
  float4 s = {0, 0, 0, 0};
#pragma unroll
  for (int kc = 0; kc < 4; ++kc) {
    float4 v = *(const float4*)(part + (long long)(b * 4 + kc) * 65536 +
                                (long long)(m0 + m) * 256 + d0 + d4);
    s.x += v.x; s.y += v.y; s.z += v.z; s.w += v.w;
  }
  tb[m][d4] = s.x; tb[m][d4 + 1] = s.y; tb[m][d4 + 2] = s.z; tb[m][d4 + 3] = s.w;
  __syncthreads();
  const int d = t >> 3, m4 = (t & 7) * 4;
  ushort4 o;
  o.x = f2bf(tb[m4][d]); o.y = f2bf(tb[m4 + 1][d]);
  o.z = f2bf(tb[m4 + 2][d]); o.w = f2bf(tb[m4 + 3][d]);
  *(ushort4*)&kvsT[(long long)b * 65536 + (long long)(d0 + d) * 256 + m0 + m4] = o;
}

// ---------------------------------------------------------------------------
// gemm64<MODE>: C = A @ B^T. Tile 64x64, N=256 fixed, batched via z.
// MODE 0: A f32 (staged to bf16), +bias, out bf16
// MODE 1: A bf16, /aux[row] (den),  out bf16
// MODE 2: A bf16, +bias,            out f32
// ---------------------------------------------------------------------------
template <int MODE>
__global__ __launch_bounds__(256) void gemm64(
    const void* __restrict__ Av, const u16* __restrict__ B, void* __restrict__ Cv,
    const float* __restrict__ aux, int K,
    long long sA, long long sB, long long sC, long long sAux) {
  __shared__ u16 As[64][40];
  __shared__ u16 Bs[64][40];
  const int bz = blockIdx.z;
  const int bm = blockIdx.x * 64, bn = blockIdx.y * 64;
  const int t = threadIdx.x;
  const int lane = t & 63, wid = t >> 6;
  const int wm = (wid >> 1) * 32, wn = (wid & 1) * 32;
  const int arow = t >> 2, acol = (t & 3) * 8;
  const int fm = lane & 15, fq = (lane >> 4) * 8, rowq = (lane >> 4) * 4;
  f32x4 acc[2][2] = {};
  for (int k0 = 0; k0 < K; k0 += 32) {
    uint4 av = {};
    float4 af0 = {}, af1 = {};
    if (MODE == 0) {
      const float* A = (const float*)Av + bz * sA;
      af0 = *(const float4*)(A + (long long)(bm + arow) * K + k0 + acol);
      af1 = *(const float4*)(A + (long long)(bm + arow) * K + k0 + acol + 4);
    } else {
      const u16* A = (const u16*)Av + bz * sA;
      av = *(const uint4*)(A + (long long)(bm + arow) * K + k0 + acol);
    }
    uint4 bv = *(const uint4*)(B + bz * sB + (long long)(bn + arow) * K + k0 + acol);
    __syncthreads();
    if (MODE == 0) {
      u16* ap = &As[arow][acol];
      ap[0] = f2bf(af0.x); ap[1] = f2bf(af0.y); ap[2] = f2bf(af0.z); ap[3] = f2bf(af0.w);
      ap[4] = f2bf(af1.x); ap[5] = f2bf(af1.y); ap[6] = f2bf(af1.z); ap[7] = f2bf(af1.w);
    } else {
      *(uint4*)&As[arow][acol] = av;
    }
    *(uint4*)&Bs[arow][acol] = bv;
    __syncthreads();
    bf16x8 a0 = *(const bf16x8*)&As[wm + fm][fq];
    bf16x8 a1 = *(const bf16x8*)&As[wm + 16 + fm][fq];
    bf16x8 b0 = *(const bf16x8*)&Bs[wn + fm][fq];
    bf16x8 b1 = *(const bf16x8*)&Bs[wn + 16 + fm][fq];
    acc[0][0] = MFMA(a0, b0, acc[0][0]);
    acc[0][1] = MFMA(a0, b1, acc[0][1]);
    acc[1][0] = MFMA(a1, b0, acc[1][0]);
    acc[1][1] = MFMA(a1, b1, acc[1][1]);
  }
#pragma unroll
  for (int mt = 0; mt < 2; ++mt) {
#pragma unroll
    for (int nt = 0; nt < 2; ++nt) {
      int col = bn + wn + nt * 16 + fm;
      int r0 = bm + wm + mt * 16 + rowq;
      float bb = (MODE != 1) ? aux[col] : 0.0f;
#pragma unroll
      for (int r = 0; r < 4; ++r) {
        long long row = r0 + r;
        float v = acc[mt][nt][r];
        if (MODE == 1) v = v / aux[sAux * bz + row];
        else v += bb;
        long long idx = sC * bz + row * 256 + col;
        if (MODE == 2) ((float*)Cv)[idx] = v;
        else ((u16*)Cv)[idx] = f2bf(v);
      }
    }
  }
}

// ---------------------------------------------------------------------------
extern "C" void kernel_launch(void* const* d_in, const int* in_sizes, int n_in,
                              void* d_out, int out_size, void* d_ws, size_t ws_size,
                              hipStream_t stream) {
  (void)in_sizes; (void)n_in; (void)out_size; (void)ws_size;
  const float* query = (const float*)d_in[0];
  const float* key = (const float*)d_in[1];
  const float* value = (const float*)d_in[2];
  // d_in[3] = mask: all-ones, unused
  const float* Wq = (const float*)d_in[4];
  const float* bq = (const float*)d_in[5];
  const float* Wk = (const float*)d_in[6];
  const float* bk = (const float*)d_in[7];
  const float* Wv = (const float*)d_in[8];
  const float* bv = (const float*)d_in[9];
  const float* Wo = (const float*)d_in[10];
  const float* bo = (const float*)d_in[11];
  const float* proj = (const float*)d_in[12];
  const float* pos = (const float*)d_in[13];

  char* w = (char*)d_ws;  // ~34.1 MB used
  u16* qs = (u16*)(w);                          // 4 MB
  u16* ks = (u16*)(w + (4 << 20));              // 4 MB
  u16* v_bf = (u16*)(w + (8 << 20));            // 4 MB
  float* xp = (float*)(w + (12 << 20));         // 8 MB f32
  u16* qp = (u16*)(w + (20 << 20));             // 4 MB
  u16* ctx = (u16*)(w + (24 << 20));            // 4 MB
  float* part = (float*)(w + (28 << 20));       // 4 MB f32 (16 x 256 x 256)
  u16* kvsT = (u16*)(w + (32 << 20));           // 512 KB
  u16* WqT = (u16*)(w + (33 << 20));            // 128 KB each
  u16* WkT = WqT + 65536;
  u16* WvT = WkT + 65536;
  u16* WoT = WvT + 65536;
  u16* projb = WoT + 65536;
  float* diag_q = (float*)(w + (34 << 20));     // 32 KB
  float* diag_k = diag_q + 8192;                // 32 KB
  float* den = diag_k + 8192;                   // 32 KB
  float* ksum = den + 8192;                     // 4 KB
  u32* mxk_enc = (u32*)(ksum + 1024);           // 16 B

  dim3 blk256(256);

  prep_w<<<dim3(8, 8, 5), dim3(32, 8), 0, stream>>>(Wq, Wk, Wv, Wo, proj,
                                                    WqT, WkT, WvT, WoT, projb);
  init_small<<<1, blk256, 0, stream>>>(ksum, mxk_enc);
  proj_rot<<<dim3(128, 1, 2), blk256, 0, stream>>>(query, key, WqT, WkT, bq, bk, pos,
                                                   qs, ks, diag_q, diag_k);
  gemm64<0><<<dim3(128, 4, 1), blk256, 0, stream>>>(value, WvT, v_bf, bv, 256, 0, 0, 0, 0);
  feat_k<<<dim3(256), blk256, 0, stream>>>(ks, projb, xp, mxk_enc);
  kvs_split<<<dim3(4, 4, 16), blk256, 0, stream>>>(xp, v_bf, diag_k, mxk_enc, part, ksum);
  reduce_kvsT<<<dim3(8, 8, 4), blk256, 0, stream>>>(part, kvsT);
  feat_q<<<dim3(256), blk256, 0, stream>>>(qs, projb, diag_q, ksum, qp, den);
  gemm64<1><<<dim3(32, 4, 4), blk256, 0, stream>>>(qp, kvsT, ctx, den, 256,
                                                   524288, 65536, 524288, 2048);
  gemm64<2><<<dim3(128, 4, 1), blk256, 0, stream>>>(ctx, WoT, d_out, bo, 256, 0, 0, 0, 0);
}